// Round 8
// baseline (23.717 us; speedup 1.0000x reference)
//
#include <hip/hip_runtime.h>
#include <math.h>

#define NV      6890
#define BLOCK   1024
#define NWAVES  (BLOCK / 64)
#define DENSITY 985.0f

typedef float v2f __attribute__((ext_vector_type(2)));

__device__ __forceinline__ float frcp(float x)  { return __builtin_amdgcn_rcpf(x); }
__device__ __forceinline__ float fsqrt(float x) { return __builtin_amdgcn_sqrtf(x); }

// ---- prep: pack faces (F,3) int32 -> (F) uint2 {i0|i1<<16, i2} ----
__global__ __launch_bounds__(256) void pack_faces_kernel(
    const int* __restrict__ faces, uint2* __restrict__ pf, int F)
{
    const int f = blockIdx.x * 256 + threadIdx.x;
    if (f < F) {
        const unsigned i0 = (unsigned)faces[3 * f + 0];
        const unsigned i1 = (unsigned)faces[3 * f + 1];
        const unsigned i2 = (unsigned)faces[3 * f + 2];
        pf[f] = make_uint2(i0 | (i1 << 16), i2);
    }
}

template<bool PACKED>
__global__ __launch_bounds__(BLOCK) void measure_kernel(
    const float* __restrict__ v,        // (B, NV, 3)
    const int*   __restrict__ faces,    // (F, 3) — used when !PACKED
    const uint2* __restrict__ pfaces,   // (F)    — used when PACKED
    const int*   __restrict__ circ_idx, // (3,)
    const int*   __restrict__ h_idx,    // (2,)
    float*       __restrict__ out,      // (B, 5)
    int F)
{
    // LDS layout: xz (float2[NV]) | y (float[NV]) | red (NWAVES*4)
    extern __shared__ float lds[];
    v2f*   xzs = reinterpret_cast<v2f*>(lds);
    float* ys  = lds + 2 * NV;
    float* red = ys + NV;

    const int b = blockIdx.x;
    const float* vb = v + (size_t)b * NV * 3;

    // ---- staging: float2 global loads, merged LDS writes (NV is even) ----
    {
        const v2f* vb2 = reinterpret_cast<const v2f*>(vb);   // 8B-aligned for all b
        const int NSLOT = NV / 2;                            // 2 verts per slot
        for (int j = threadIdx.x; j < NSLOT; j += BLOCK) {
            const v2f a = vb2[3 * j + 0];   // (x0, y0)
            const v2f m = vb2[3 * j + 1];   // (z0, x1)
            const v2f c = vb2[3 * j + 2];   // (y1, z1)
            ys[2 * j + 0] = a.y;
            ys[2 * j + 1] = c.x;
            xzs[2 * j + 0] = (v2f){ a.x, m.x };
            xzs[2 * j + 1] = (v2f){ m.y, c.y };
        }
    }
    __syncthreads();

    const float pys[3] = { ys[circ_idx[0]], ys[circ_idx[1]], ys[circ_idx[2]] };

    float vol = 0.0f;
    float circ[3] = {0.0f, 0.0f, 0.0f};

    #pragma unroll 2
    for (int f = threadIdx.x; f < F; f += BLOCK) {
        int i0, i1, i2;
        if (PACKED) {
            const uint2 w = pfaces[f];       // one coalesced dwordx2
            i0 = (int)(w.x & 0xffffu);
            i1 = (int)(w.x >> 16);
            i2 = (int)(w.y & 0xffffu);
        } else {
            i0 = faces[3 * f + 0];
            i1 = faces[3 * f + 1];
            i2 = faces[3 * f + 2];
        }

        const float y0 = ys[i0], y1 = ys[i1], y2 = ys[i2];
        const v2f xz0 = xzs[i0];   // {x, z}
        const v2f xz1 = xzs[i1];
        const v2f xz2 = xzs[i2];

        // signed volume term: v0 . (v1 x v2)
        {
            const float cx = y1 * xz2.y - xz1.y * y2;
            const float cy = xz1.y * xz2.x - xz1.x * xz2.y;
            const float cz = xz1.x * y2 - y1 * xz2.x;
            vol += xz0.x * cx + y0 * cy + xz0.y * cz;
        }

        // plane-invariant per-edge slopes; L = |d_odd| * |g_a - g_b|
        const v2f g01 = (xz1 - xz0) * frcp(y0 - y1);
        const v2f g12 = (xz2 - xz1) * frcp(y1 - y2);
        const v2f g20 = (xz0 - xz2) * frcp(y2 - y0);

        const v2f w0 = g01 - g20;   // odd = v0
        const v2f w1 = g01 - g12;   // odd = v1
        const v2f w2 = g12 - g20;   // odd = v2
        const float h0 = fsqrt(fmaf(w0.x, w0.x, w0.y * w0.y));
        const float h1 = fsqrt(fmaf(w1.x, w1.x, w1.y * w1.y));
        const float h2 = fsqrt(fmaf(w2.x, w2.x, w2.y * w2.y));

        #pragma unroll
        for (int p = 0; p < 3; ++p) {
            const float py = pys[p];
            const float d0 = y0 - py;
            const float d1 = y1 - py;
            const float d2 = y2 - py;
            const bool c0 = (d0 * d1) < 0.0f;
            const bool c1 = (d1 * d2) < 0.0f;
            const bool c2 = (d2 * d0) < 0.0f;

            // odd vertex: 0 iff c0&c2, 1 iff c0&c1, 2 iff c1&c2
            float dsel = c2 ? d0 : d1;
            float hsel = c2 ? h0 : h1;
            dsel = c0 ? dsel : d2;
            hsel = c0 ? hsel : h2;
            // pairwise test (NOT c0||c1||c2): exactly-one-crossing occurs when a
            // vertex lies exactly on the plane (e.g. the circ vertex itself).
            const bool valid = (c0 && c1) || (c1 && c2) || (c2 && c0);

            const float L = fabsf(dsel) * hsel;
            circ[p] += valid ? L : 0.0f;
        }
    }

    // wave-level reduction (wave = 64)
    #pragma unroll
    for (int off = 32; off > 0; off >>= 1) {
        vol     += __shfl_down(vol,     off);
        circ[0] += __shfl_down(circ[0], off);
        circ[1] += __shfl_down(circ[1], off);
        circ[2] += __shfl_down(circ[2], off);
    }
    const int lane = threadIdx.x & 63;
    const int wid  = threadIdx.x >> 6;
    if (lane == 0) {
        red[wid * 4 + 0] = vol;
        red[wid * 4 + 1] = circ[0];
        red[wid * 4 + 2] = circ[1];
        red[wid * 4 + 3] = circ[2];
    }
    __syncthreads();

    if (threadIdx.x == 0) {
        float tv = 0.f, t0 = 0.f, t1 = 0.f, t2 = 0.f;
        for (int w = 0; w < NWAVES; ++w) {
            tv += red[w * 4 + 0];
            t0 += red[w * 4 + 1];
            t1 += red[w * 4 + 2];
            t2 += red[w * 4 + 3];
        }
        const float mass = fabsf(tv / 6.0f) * DENSITY;
        const float hy0 = ys[h_idx[0]];
        const float hy1 = ys[h_idx[1]];
        out[b * 5 + 0] = mass;
        out[b * 5 + 1] = fabsf(hy0 - hy1);
        out[b * 5 + 2] = t0;
        out[b * 5 + 3] = t1;
        out[b * 5 + 4] = t2;
    }
}

extern "C" void kernel_launch(void* const* d_in, const int* in_sizes, int n_in,
                              void* d_out, int out_size, void* d_ws, size_t ws_size,
                              hipStream_t stream) {
    const float* v        = (const float*)d_in[0];
    const int*   faces    = (const int*)d_in[1];
    const int*   circ_idx = (const int*)d_in[2];
    const int*   h_idx    = (const int*)d_in[3];
    float*       out      = (float*)d_out;

    const int B = in_sizes[0] / (NV * 3);   // 256
    const int F = in_sizes[1] / 3;          // 13776

    const size_t lds_bytes = (size_t)(3 * NV + NWAVES * 4) * sizeof(float);

    if (ws_size >= (size_t)F * sizeof(uint2)) {
        uint2* pf = (uint2*)d_ws;
        pack_faces_kernel<<<(F + 255) / 256, 256, 0, stream>>>(faces, pf, F);
        measure_kernel<true><<<B, BLOCK, lds_bytes, stream>>>(v, faces, pf, circ_idx, h_idx, out, F);
    } else {
        measure_kernel<false><<<B, BLOCK, lds_bytes, stream>>>(v, faces, (const uint2*)nullptr, circ_idx, h_idx, out, F);
    }
}

// Round 9
// 19.055 us; speedup vs baseline: 1.2447x; 1.2447x over previous
//
#include <hip/hip_runtime.h>
#include <math.h>

#define NV      6890
#define BLOCK   1024
#define NWAVES  (BLOCK / 64)
#define DENSITY 985.0f

typedef float v2f __attribute__((ext_vector_type(2)));

__device__ __forceinline__ float frcp(float x)  { return __builtin_amdgcn_rcpf(x); }
__device__ __forceinline__ float fsqrt(float x) { return __builtin_amdgcn_sqrtf(x); }

__global__ __launch_bounds__(BLOCK) void measure_kernel(
    const float* __restrict__ v,        // (B, NV, 3)
    const int*   __restrict__ faces,    // (F, 3)
    const int*   __restrict__ circ_idx, // (3,)
    const int*   __restrict__ h_idx,    // (2,)
    float*       __restrict__ out,      // (B, 5)
    int F)
{
    // LDS layout: vert (float4[NV]) | red (NWAVES*4)
    extern __shared__ float lds[];
    float4* vert = reinterpret_cast<float4*>(lds);
    float*  red  = lds + 4 * NV;

    const int b = blockIdx.x;
    const float* vb = v + (size_t)b * NV * 3;

    // ---- staging: float2 global loads -> float4 LDS writes (NV even) ----
    {
        const v2f* vb2 = reinterpret_cast<const v2f*>(vb);   // 8B-aligned for all b
        const int NSLOT = NV / 2;
        for (int j = threadIdx.x; j < NSLOT; j += BLOCK) {
            const v2f a = vb2[3 * j + 0];   // (x0, y0)
            const v2f m = vb2[3 * j + 1];   // (z0, x1)
            const v2f c = vb2[3 * j + 2];   // (y1, z1)
            vert[2 * j + 0] = make_float4(a.x, a.y, m.x, 0.0f);
            vert[2 * j + 1] = make_float4(m.y, c.x, c.y, 0.0f);
        }
    }
    __syncthreads();

    const float pys[3] = { vert[circ_idx[0]].y,
                           vert[circ_idx[1]].y,
                           vert[circ_idx[2]].y };

    float vol = 0.0f;
    float circ[3] = {0.0f, 0.0f, 0.0f};

    // one face's full contribution (volume + 3 plane segments)
    auto face_body = [&](int i0, int i1, int i2) {
        const float4 V0 = vert[i0];         // ds_read_b128 x3
        const float4 V1 = vert[i1];
        const float4 V2 = vert[i2];

        // signed volume term: v0 . (v1 x v2)
        {
            const float cx = V1.y * V2.z - V1.z * V2.y;
            const float cy = V1.z * V2.x - V1.x * V2.z;
            const float cz = V1.x * V2.y - V1.y * V2.x;
            vol += V0.x * cx + V0.y * cy + V0.z * cz;
        }

        // plane-invariant per-edge slopes; L = |d_odd| * |g_a - g_b|
        const v2f xz0 = { V0.x, V0.z };
        const v2f xz1 = { V1.x, V1.z };
        const v2f xz2 = { V2.x, V2.z };
        const v2f g01 = (xz1 - xz0) * frcp(V0.y - V1.y);
        const v2f g12 = (xz2 - xz1) * frcp(V1.y - V2.y);
        const v2f g20 = (xz0 - xz2) * frcp(V2.y - V0.y);

        const v2f w0 = g01 - g20;   // odd = v0
        const v2f w1 = g01 - g12;   // odd = v1
        const v2f w2 = g12 - g20;   // odd = v2
        const float h0 = fsqrt(fmaf(w0.x, w0.x, w0.y * w0.y));
        const float h1 = fsqrt(fmaf(w1.x, w1.x, w1.y * w1.y));
        const float h2 = fsqrt(fmaf(w2.x, w2.x, w2.y * w2.y));

        #pragma unroll
        for (int p = 0; p < 3; ++p) {
            const float py = pys[p];
            const float d0 = V0.y - py;
            const float d1 = V1.y - py;
            const float d2 = V2.y - py;
            const bool c0 = (d0 * d1) < 0.0f;
            const bool c1 = (d1 * d2) < 0.0f;
            const bool c2 = (d2 * d0) < 0.0f;

            // odd vertex: 0 iff c0&c2, 1 iff c0&c1, 2 iff c1&c2
            float dsel = c2 ? d0 : d1;
            float hsel = c2 ? h0 : h1;
            dsel = c0 ? dsel : d2;
            hsel = c0 ? hsel : h2;
            // pairwise test (NOT c0||c1||c2): a vertex exactly on the plane
            // (e.g. the circ vertex itself) gives exactly one crossing.
            const bool valid = (c0 && c1) || (c1 && c2) || (c2 && c0);

            const float L = fabsf(dsel) * hsel;
            circ[p] += valid ? L : 0.0f;
        }
    };

    // paired contiguous faces: thread q handles faces 2q, 2q+1.
    // 6 indices = 3x int2 loads (8B-aligned: byte offset 24q).
    const int npairs = F / 2;               // F = 13776 -> 6888
    #pragma unroll 2
    for (int q = threadIdx.x; q < npairs; q += BLOCK) {
        const int2* fp = reinterpret_cast<const int2*>(faces + 6 * q);
        const int2 wA = fp[0];              // i0a, i1a
        const int2 wB = fp[1];              // i2a, i0b
        const int2 wC = fp[2];              // i1b, i2b
        face_body(wA.x, wA.y, wB.x);
        face_body(wB.y, wC.x, wC.y);
    }

    // wave-level reduction (wave = 64)
    #pragma unroll
    for (int off = 32; off > 0; off >>= 1) {
        vol     += __shfl_down(vol,     off);
        circ[0] += __shfl_down(circ[0], off);
        circ[1] += __shfl_down(circ[1], off);
        circ[2] += __shfl_down(circ[2], off);
    }
    const int lane = threadIdx.x & 63;
    const int wid  = threadIdx.x >> 6;
    if (lane == 0) {
        red[wid * 4 + 0] = vol;
        red[wid * 4 + 1] = circ[0];
        red[wid * 4 + 2] = circ[1];
        red[wid * 4 + 3] = circ[2];
    }
    __syncthreads();

    if (threadIdx.x == 0) {
        float tv = 0.f, t0 = 0.f, t1 = 0.f, t2 = 0.f;
        for (int w = 0; w < NWAVES; ++w) {
            tv += red[w * 4 + 0];
            t0 += red[w * 4 + 1];
            t1 += red[w * 4 + 2];
            t2 += red[w * 4 + 3];
        }
        const float mass = fabsf(tv / 6.0f) * DENSITY;
        const float hy0 = vert[h_idx[0]].y;
        const float hy1 = vert[h_idx[1]].y;
        out[b * 5 + 0] = mass;
        out[b * 5 + 1] = fabsf(hy0 - hy1);
        out[b * 5 + 2] = t0;
        out[b * 5 + 3] = t1;
        out[b * 5 + 4] = t2;
    }
}

extern "C" void kernel_launch(void* const* d_in, const int* in_sizes, int n_in,
                              void* d_out, int out_size, void* d_ws, size_t ws_size,
                              hipStream_t stream) {
    const float* v        = (const float*)d_in[0];
    const int*   faces    = (const int*)d_in[1];
    const int*   circ_idx = (const int*)d_in[2];
    const int*   h_idx    = (const int*)d_in[3];
    float*       out      = (float*)d_out;

    const int B = in_sizes[0] / (NV * 3);   // 256
    const int F = in_sizes[1] / 3;          // 13776

    const size_t lds_bytes = (size_t)(4 * NV + NWAVES * 4) * sizeof(float);
    measure_kernel<<<B, BLOCK, lds_bytes, stream>>>(v, faces, circ_idx, h_idx, out, F);
}

// Round 11
// 16.483 us; speedup vs baseline: 1.4389x; 1.1561x over previous
//
#include <hip/hip_runtime.h>
#include <math.h>

#define NV      6890
#define BLOCK   1024
#define NWAVES  (BLOCK / 64)
#define DENSITY 985.0f

typedef float v2f __attribute__((ext_vector_type(2)));

__device__ __forceinline__ float frcp(float x)  { return __builtin_amdgcn_rcpf(x); }
__device__ __forceinline__ float fsqrt(float x) { return __builtin_amdgcn_sqrtf(x); }

__device__ __forceinline__ unsigned bf16rtn_hi(float f) {   // bf16(f) in high 16 bits
    return (__float_as_uint(f) + 0x8000u) & 0xffff0000u;
}
__device__ __forceinline__ unsigned bf16rtn_lo(float f) {   // bf16(f) in low 16 bits
    return (__float_as_uint(f) + 0x8000u) >> 16;
}

__global__ __launch_bounds__(BLOCK) void measure_kernel(
    const float* __restrict__ v,        // (B, NV, 3)
    const int*   __restrict__ faces,    // (F, 3)
    const int*   __restrict__ circ_idx, // (3,)
    const int*   __restrict__ h_idx,    // (2,)
    float*       __restrict__ out,      // (B, 5)
    int F)
{
    // LDS: vslot[i] = { fp32 y , bf16x2 (x,z) } = 8 B  | red (NWAVES*4 floats)
    extern __shared__ float lds[];
    uint2* vslot = reinterpret_cast<uint2*>(lds);
    float* red   = lds + 2 * NV;

    const int b = blockIdx.x;
    const float* vb = v + (size_t)b * NV * 3;

    // ---- staging: float2 global loads -> packed 8B LDS slots (NV even) ----
    {
        const v2f* vb2 = reinterpret_cast<const v2f*>(vb);   // 8B-aligned for all b
        const int NSLOT = NV / 2;
        for (int j = threadIdx.x; j < NSLOT; j += BLOCK) {
            const v2f a = vb2[3 * j + 0];   // (x0, y0)
            const v2f m = vb2[3 * j + 1];   // (z0, x1)
            const v2f c = vb2[3 * j + 2];   // (y1, z1)
            // round-to-nearest bf16 for x,z; y kept exact fp32
            const unsigned p0 = bf16rtn_hi(a.x) | bf16rtn_lo(m.x);
            const unsigned p1 = bf16rtn_hi(m.y) | bf16rtn_lo(c.y);
            vslot[2 * j + 0] = make_uint2(__float_as_uint(a.y), p0);
            vslot[2 * j + 1] = make_uint2(__float_as_uint(c.x), p1);
        }
    }
    __syncthreads();

    const float pys[3] = { __uint_as_float(vslot[circ_idx[0]].x),
                           __uint_as_float(vslot[circ_idx[1]].x),
                           __uint_as_float(vslot[circ_idx[2]].x) };

    float vol = 0.0f;
    float circ[3] = {0.0f, 0.0f, 0.0f};

    #pragma unroll 2
    for (int f = threadIdx.x; f < F; f += BLOCK) {
        const int i0 = faces[3 * f + 0];
        const int i1 = faces[3 * f + 1];
        const int i2 = faces[3 * f + 2];

        const uint2 s0 = vslot[i0];         // one ds_read_b64 per vertex
        const uint2 s1 = vslot[i1];
        const uint2 s2 = vslot[i2];
        const float y0 = __uint_as_float(s0.x);
        const float y1 = __uint_as_float(s1.x);
        const float y2 = __uint_as_float(s2.x);
        const v2f xz0 = { __uint_as_float(s0.y & 0xffff0000u), __uint_as_float(s0.y << 16) };
        const v2f xz1 = { __uint_as_float(s1.y & 0xffff0000u), __uint_as_float(s1.y << 16) };
        const v2f xz2 = { __uint_as_float(s2.y & 0xffff0000u), __uint_as_float(s2.y << 16) };

        // signed volume term: v0 . (v1 x v2)   (x,z bf16-rounded, y exact)
        {
            const float cx = y1 * xz2.y - xz1.y * y2;
            const float cy = xz1.y * xz2.x - xz1.x * xz2.y;
            const float cz = xz1.x * y2 - y1 * xz2.x;
            vol += xz0.x * cx + y0 * cy + xz0.y * cz;
        }

        // plane-invariant per-edge slopes; L = |d_odd| * |g_a - g_b|.
        // NaN-safety invariant: each h_i is built DIRECTLY from the slopes of
        // its own two crossing edges (crossing => y_a != y_b => slope finite).
        // Degenerate faces (repeated index) give NaN/inf in the OTHER slopes,
        // which the selection below never picks.  Do NOT use w1 = w0 - w2.
        const v2f g01 = (xz1 - xz0) * frcp(y0 - y1);
        const v2f g12 = (xz2 - xz1) * frcp(y1 - y2);
        const v2f g20 = (xz0 - xz2) * frcp(y2 - y0);

        const v2f w0 = g01 - g20;           // odd = v0 (edges 01 & 20)
        const v2f w1 = g01 - g12;           // odd = v1 (edges 01 & 12)
        const v2f w2 = g12 - g20;           // odd = v2 (edges 12 & 20)
        const float h0 = fsqrt(fmaf(w0.x, w0.x, w0.y * w0.y));
        const float h1 = fsqrt(fmaf(w1.x, w1.x, w1.y * w1.y));
        const float h2 = fsqrt(fmaf(w2.x, w2.x, w2.y * w2.y));

        #pragma unroll
        for (int p = 0; p < 3; ++p) {
            const float py = pys[p];
            // XOR sign tests (no multiplies); exact y's, so ties (y==py or
            // y0==y1) never count as crossings -> selected h is finite.
            const bool b0 = y0 < py;
            const bool b1 = y1 < py;
            const bool b2 = y2 < py;
            const bool c0 = b0 != b1;       // edge v0->v1 crosses
            const bool c1 = b1 != b2;       // edge v1->v2
            const bool c2 = b2 != b0;       // edge v2->v0

            const float d0 = y0 - py;
            const float d1 = y1 - py;
            const float d2 = y2 - py;

            // odd vertex: 0 iff c0&c2, 1 iff c0&c1, 2 iff c1&c2
            float dsel = c2 ? d0 : d1;
            float hsel = c2 ? h0 : h1;
            dsel = c0 ? dsel : d2;
            hsel = c0 ? hsel : h2;
            // XOR-consistency (c0^c1^c2 == 0) => count is 0 or 2: OR suffices
            const bool valid = c0 || c1 || c2;

            const float L = fabsf(dsel) * hsel;
            circ[p] += valid ? L : 0.0f;
        }
    }

    // wave-level reduction (wave = 64)
    #pragma unroll
    for (int off = 32; off > 0; off >>= 1) {
        vol     += __shfl_down(vol,     off);
        circ[0] += __shfl_down(circ[0], off);
        circ[1] += __shfl_down(circ[1], off);
        circ[2] += __shfl_down(circ[2], off);
    }
    const int lane = threadIdx.x & 63;
    const int wid  = threadIdx.x >> 6;
    if (lane == 0) {
        red[wid * 4 + 0] = vol;
        red[wid * 4 + 1] = circ[0];
        red[wid * 4 + 2] = circ[1];
        red[wid * 4 + 3] = circ[2];
    }
    __syncthreads();

    // parallel epilogue: threads 0..3 reduce, thread 4 does height
    const int tid = threadIdx.x;
    if (tid < 4) {
        float s = 0.0f;
        for (int w = 0; w < NWAVES; ++w) s += red[w * 4 + tid];
        if (tid == 0) out[b * 5 + 0] = fabsf(s / 6.0f) * DENSITY;  // mass
        else          out[b * 5 + 1 + tid] = s;                    // circ0..2
    } else if (tid == 4) {
        const float hy0 = __uint_as_float(vslot[h_idx[0]].x);
        const float hy1 = __uint_as_float(vslot[h_idx[1]].x);
        out[b * 5 + 1] = fabsf(hy0 - hy1);
    }
}

extern "C" void kernel_launch(void* const* d_in, const int* in_sizes, int n_in,
                              void* d_out, int out_size, void* d_ws, size_t ws_size,
                              hipStream_t stream) {
    const float* v        = (const float*)d_in[0];
    const int*   faces    = (const int*)d_in[1];
    const int*   circ_idx = (const int*)d_in[2];
    const int*   h_idx    = (const int*)d_in[3];
    float*       out      = (float*)d_out;

    const int B = in_sizes[0] / (NV * 3);   // 256
    const int F = in_sizes[1] / 3;          // 13776

    const size_t lds_bytes = (size_t)(2 * NV + NWAVES * 4) * sizeof(float);
    measure_kernel<<<B, BLOCK, lds_bytes, stream>>>(v, faces, circ_idx, h_idx, out, F);
}